// Round 6
// baseline (3583.487 us; speedup 1.0000x reference)
//
#include <hip/hip_runtime.h>
#include <hip/hip_bf16.h>
#include <stdint.h>

typedef short   s16x8  __attribute__((ext_vector_type(8)));
typedef float   f32x4a __attribute__((ext_vector_type(4)));
typedef unsigned short u16x4 __attribute__((ext_vector_type(4)));
typedef int     i32x4  __attribute__((ext_vector_type(4)));

#define D_IN   4096
#define D_OUT  4096
#define RANK   16
#define KEXT   4128   // 4096 + 16 (lora) + 16 (zero pad) = 129 * 32
#define MROWS  8192   // 4 * 2048
#define NTT    129    // K-tiles of 32

__device__ __forceinline__ uint16_t f32_to_bf16(float f) {
  union { float f; uint32_t u; } v; v.f = f;
  uint32_t u = v.u;
  return (uint16_t)((u + 0x7FFFu + ((u >> 16) & 1u)) >> 16);  // RNE
}

__device__ __forceinline__ void gload16(void* lds, const void* g) {
  __builtin_amdgcn_global_load_lds(
      (const __attribute__((address_space(1))) uint32_t*)g,
      (__attribute__((address_space(3))) uint32_t*)lds, 16, 0, 0);
}

// ---- 1) x fp32 -> bf16 into x_ext (row stride KEXT) --------------------
extern "C" __global__ void k_conv_x(const float* __restrict__ x,
                                    uint16_t* __restrict__ xext) {
  int64_t idx = (int64_t)blockIdx.x * blockDim.x + threadIdx.x;  // float4 index
  const int64_t total  = (int64_t)MROWS * (D_IN / 4);
  const int64_t stride = (int64_t)gridDim.x * blockDim.x;
  for (; idx < total; idx += stride) {
    int64_t m = idx >> 10;              // D_IN/4 = 1024
    int k4 = (int)(idx & 1023);
    f32x4a v = *(const f32x4a*)(x + m * D_IN + (int64_t)k4 * 4);
    u16x4 o;
#pragma unroll
    for (int j = 0; j < 4; j++) o[j] = f32_to_bf16(v[j]);
    *(u16x4*)(xext + m * KEXT + k4 * 4) = o;
  }
}

// ---- 2) xA = x_bf16 @ loraA^T via MFMA, into x_ext cols [4096,4128) ----
extern "C" __global__ __launch_bounds__(256) void k_xa(
    const uint16_t* __restrict__ xext_ro, uint16_t* __restrict__ xext_rw,
    const float* __restrict__ loraA) {
  const int tid = threadIdx.x, w = tid >> 6, l = tid & 63;
  const int l15 = l & 15, lk = l >> 4;
  const int64_t row0 = (int64_t)blockIdx.x * 64 + w * 16;
  f32x4a acc = {0.f, 0.f, 0.f, 0.f};
  const uint16_t* xrow = xext_ro + (row0 + l15) * KEXT + lk * 8;
  const float*    arow = loraA + (int64_t)l15 * D_IN + lk * 8;
  for (int k0 = 0; k0 < D_IN; k0 += 32) {
    s16x8 af = *(const s16x8*)(xrow + k0);
    s16x8 bf;
#pragma unroll
    for (int j = 0; j < 8; j++) bf[j] = (short)f32_to_bf16(arow[k0 + j]);
    acc = __builtin_amdgcn_mfma_f32_16x16x32_bf16(af, bf, acc, 0, 0, 0);
  }
#pragma unroll
  for (int reg = 0; reg < 4; reg++) {
    int64_t m = row0 + lk * 4 + reg;
    xext_rw[m * KEXT + D_IN + l15]        = f32_to_bf16(acc[reg]);
    xext_rw[m * KEXT + D_IN + RANK + l15] = (uint16_t)0;  // zero pad
  }
}

// ---- 3) qweight int -> bf16 + LoRA-B tail into w_ext -------------------
extern "C" __global__ void k_conv_w(const int* __restrict__ qw,
                                    const int* __restrict__ qscale,
                                    const float* __restrict__ meta,
                                    const float* __restrict__ loraB,
                                    uint16_t* __restrict__ wext) {
  const int n = blockIdx.x, t = threadIdx.x;
  const int* row  = qw   + (int64_t)n * D_IN;
  uint16_t*  orow = wext + (int64_t)n * KEXT;
  const int base = t * 16;
#pragma unroll
  for (int j = 0; j < 4; j++) {
    i32x4 v = *(const i32x4*)(row + base + j * 4);
    u16x4 o;
#pragma unroll
    for (int e = 0; e < 4; e++) o[e] = f32_to_bf16((float)v[e]);  // exact
    *(u16x4*)(orow + base + j * 4) = o;
  }
  if (t < RANK) {
    float sr = (float)qscale[n] * meta[0];
    orow[D_IN + t] = f32_to_bf16(2.0f * loraB[n * RANK + t] / sr);
  } else if (t < 2 * RANK) {
    orow[D_IN + t] = (uint16_t)0;  // zero pad
  }
}

// ---- 4) main GEMM: 256x256 tile, BK=32, dbuf, 2 blocks/CU --------------
// 8 waves (2m x 4n), per-wave 128x64. LDS 64 KB: A/B x 2 dbuf x 16 KB ->
// 2 blocks/CU (16 waves/CU): when one block parks at vmcnt/barrier the
// other block's waves keep the MFMA pipe fed (m114 overlap). 129 uniform
// K-tiles (4128 = 129*32) -> no LoRA tail special case. Stage kt+1 issued
// BEFORE kt's compute so ~2.5k cyc of MFMA covers the load latency.
extern "C" __global__ __launch_bounds__(512, 4) void k_gemm(
    const uint16_t* __restrict__ A, const uint16_t* __restrict__ B,
    const int* __restrict__ qscale, const float* __restrict__ meta,
    const float* __restrict__ bias, float* __restrict__ out) {
  extern __shared__ char ldsc[];               // 65536 B
  char* aB = ldsc;                             // [2][16384]
  char* bB = ldsc + 32768;                     // [2][16384]

  const int tid = threadIdx.x;
  const int bid = blockIdx.x;                  // 512 blocks, 512%8==0
  const int xcd = bid & 7, loc = bid >> 3;
  const int mtile = xcd * 4 + (loc & 3);       // 0..31
  const int ntile = loc >> 2;                  // 0..15

  const int w = tid >> 6, l = tid & 63;
  const int wm = w >> 2, wn = w & 3;
  const int l15 = l & 15, lk = l >> 4;
  const int fro = lk * 256 + l15 * 16;         // frag byte offset in 1024-B run

  const uint16_t* Ag = A + (int64_t)mtile * 256 * KEXT;
  const uint16_t* Bg = B + (int64_t)ntile * 256 * KEXT;

  // staging granule g (2 calls x 512 threads = 1024 x 16 B = 16 KB):
  // run rb=g>>6, lk=(g>>4)&3, row16=g&15 -> row = rb*16+row16.
  const int row_lo = ((tid >> 6) << 4) | (tid & 15);           // 0..127
  const int64_t s_lo = (int64_t)row_lo * KEXT + ((tid >> 4) & 3) * 8;
  const int64_t s_hi = s_lo + (int64_t)128 * KEXT;

#define STG(bufp, gp, kb) {                                          \
    gload16((bufp) + (size_t)tid * 16,         (gp) + (kb) + s_lo);  \
    gload16((bufp) + (size_t)(512 + tid) * 16, (gp) + (kb) + s_hi); }

  f32x4a acc[8][4];
#pragma unroll
  for (int i = 0; i < 8; i++)
#pragma unroll
    for (int j = 0; j < 4; j++) acc[i][j] = (f32x4a){0.f, 0.f, 0.f, 0.f};

  // prologue: stage tile 0 into buf0
  STG(aB, Ag, 0); STG(bB, Bg, 0);
  asm volatile("s_waitcnt vmcnt(0)" ::: "memory");
  asm volatile("s_barrier" ::: "memory");

  for (int kt = 0; kt < NTT; ++kt) {
    const int cur = kt & 1;
    const char* cA = aB + cur * 16384;
    const char* cB = bB + cur * 16384;
    char* nA = aB + (cur ^ 1) * 16384;
    char* nB = bB + (cur ^ 1) * 16384;
    const bool st = (kt + 1 < NTT);
    const int64_t kb = (int64_t)(kt + 1) * 32;

    // issue next-tile staging first: MFMA below covers its latency
    if (st) { STG(nA, Ag, kb); STG(nB, Bg, kb); }

    s16x8 bf[4], af[8];
#pragma unroll
    for (int ni = 0; ni < 4; ++ni)
      bf[ni] = *(const s16x8*)(cB + (wn * 4 + ni) * 1024 + fro);
#pragma unroll
    for (int mi = 0; mi < 8; ++mi)
      af[mi] = *(const s16x8*)(cA + (wm * 8 + mi) * 1024 + fro);

    __builtin_amdgcn_s_setprio(1);
#pragma unroll
    for (int mi = 0; mi < 8; ++mi)
#pragma unroll
      for (int ni = 0; ni < 4; ++ni)
        acc[mi][ni] = __builtin_amdgcn_mfma_f32_16x16x32_bf16(
            af[mi], bf[ni], acc[mi][ni], 0, 0, 0);
    __builtin_amdgcn_s_setprio(0);

    if (st) {
      asm volatile("s_waitcnt vmcnt(0)" ::: "memory");
      asm volatile("s_barrier" ::: "memory");
    }
  }

  // epilogue: out = acc * (qscale[n]*meta) + bias[n]
  const float mv = meta[0];
  const int64_t mrow0 = (int64_t)mtile * 256 + wm * 128;
  const int ncol0 = ntile * 256 + wn * 64;
#pragma unroll
  for (int ni = 0; ni < 4; ++ni) {
    int n = ncol0 + ni * 16 + l15;
    float sr = (float)qscale[n] * mv;
    float bv = bias[n];
#pragma unroll
    for (int mi = 0; mi < 8; ++mi) {
      float* op = out + (mrow0 + mi * 16 + lk * 4) * (int64_t)D_OUT + n;
#pragma unroll
      for (int reg = 0; reg < 4; reg++)
        op[(int64_t)reg * D_OUT] = acc[mi][ni][reg] * sr + bv;
    }
  }
#undef STG
}

extern "C" void kernel_launch(void* const* d_in, const int* in_sizes, int n_in,
                              void* d_out, int out_size, void* d_ws, size_t ws_size,
                              hipStream_t stream) {
  const float* x    = (const float*)d_in[0];
  const int*   qw   = (const int*)d_in[1];
  const int*   qs   = (const int*)d_in[2];
  const float* meta = (const float*)d_in[3];
  const float* bias = (const float*)d_in[4];
  const float* lA   = (const float*)d_in[5];
  const float* lB   = (const float*)d_in[6];
  float* out = (float*)d_out;

  uint16_t* xext = (uint16_t*)d_ws;                       // 8192*4128*2 B
  uint16_t* wext = xext + (size_t)MROWS * KEXT;           // 4096*4128*2 B
  const size_t need = ((size_t)MROWS + D_OUT) * KEXT * 2; // 101,449,728 B
  if (ws_size < need) return;

  const int lds_bytes = 65536;                            // 64 KB -> 2 blk/CU
  (void)hipFuncSetAttribute((const void*)k_gemm,
                            hipFuncAttributeMaxDynamicSharedMemorySize,
                            lds_bytes);

  k_conv_x<<<2048, 256, 0, stream>>>(x, xext);
  k_xa<<<MROWS / 64, 256, 0, stream>>>(xext, xext, lA);
  k_conv_w<<<D_OUT, 256, 0, stream>>>(qw, qs, meta, lB, wext);
  k_gemm<<<512, 512, lds_bytes, stream>>>(xext, wext, qs, meta, bias, out);
}

// Round 7
// 957.492 us; speedup vs baseline: 3.7426x; 3.7426x over previous
//
#include <hip/hip_runtime.h>
#include <hip/hip_bf16.h>
#include <stdint.h>

typedef short   s16x8  __attribute__((ext_vector_type(8)));
typedef float   f32x4a __attribute__((ext_vector_type(4)));
typedef unsigned short u16x4 __attribute__((ext_vector_type(4)));
typedef int     i32x4  __attribute__((ext_vector_type(4)));

#define D_IN   4096
#define D_OUT  4096
#define RANK   16
#define KEXT   4128   // 4096 + 16 (lora) + 16 (zero pad) = 129 * 32
#define MROWS  8192   // 4 * 2048
#define NTT    129    // K-tiles of 32

__device__ __forceinline__ uint16_t f32_to_bf16(float f) {
  union { float f; uint32_t u; } v; v.f = f;
  uint32_t u = v.u;
  return (uint16_t)((u + 0x7FFFu + ((u >> 16) & 1u)) >> 16);  // RNE
}

__device__ __forceinline__ void gload16(void* lds, const void* g) {
  __builtin_amdgcn_global_load_lds(
      (const __attribute__((address_space(1))) uint32_t*)g,
      (__attribute__((address_space(3))) uint32_t*)lds, 16, 0, 0);
}

// ---- 1) x fp32 -> bf16 into x_ext (row stride KEXT) --------------------
extern "C" __global__ void k_conv_x(const float* __restrict__ x,
                                    uint16_t* __restrict__ xext) {
  int64_t idx = (int64_t)blockIdx.x * blockDim.x + threadIdx.x;  // float4 index
  const int64_t total  = (int64_t)MROWS * (D_IN / 4);
  const int64_t stride = (int64_t)gridDim.x * blockDim.x;
  for (; idx < total; idx += stride) {
    int64_t m = idx >> 10;              // D_IN/4 = 1024
    int k4 = (int)(idx & 1023);
    f32x4a v = *(const f32x4a*)(x + m * D_IN + (int64_t)k4 * 4);
    u16x4 o;
#pragma unroll
    for (int j = 0; j < 4; j++) o[j] = f32_to_bf16(v[j]);
    *(u16x4*)(xext + m * KEXT + k4 * 4) = o;
  }
}

// ---- 2) xA = x_bf16 @ loraA^T via MFMA, into x_ext cols [4096,4128) ----
extern "C" __global__ __launch_bounds__(256) void k_xa(
    const uint16_t* __restrict__ xext_ro, uint16_t* __restrict__ xext_rw,
    const float* __restrict__ loraA) {
  const int tid = threadIdx.x, w = tid >> 6, l = tid & 63;
  const int l15 = l & 15, lk = l >> 4;
  const int64_t row0 = (int64_t)blockIdx.x * 64 + w * 16;
  f32x4a acc = {0.f, 0.f, 0.f, 0.f};
  const uint16_t* xrow = xext_ro + (row0 + l15) * KEXT + lk * 8;
  const float*    arow = loraA + (int64_t)l15 * D_IN + lk * 8;
  for (int k0 = 0; k0 < D_IN; k0 += 32) {
    s16x8 af = *(const s16x8*)(xrow + k0);
    s16x8 bf;
#pragma unroll
    for (int j = 0; j < 8; j++) bf[j] = (short)f32_to_bf16(arow[k0 + j]);
    acc = __builtin_amdgcn_mfma_f32_16x16x32_bf16(af, bf, acc, 0, 0, 0);
  }
#pragma unroll
  for (int reg = 0; reg < 4; reg++) {
    int64_t m = row0 + lk * 4 + reg;
    xext_rw[m * KEXT + D_IN + l15]        = f32_to_bf16(acc[reg]);
    xext_rw[m * KEXT + D_IN + RANK + l15] = (uint16_t)0;  // zero pad
  }
}

// ---- 3) qweight int -> bf16 + LoRA-B tail into w_ext -------------------
extern "C" __global__ void k_conv_w(const int* __restrict__ qw,
                                    const int* __restrict__ qscale,
                                    const float* __restrict__ meta,
                                    const float* __restrict__ loraB,
                                    uint16_t* __restrict__ wext) {
  const int n = blockIdx.x, t = threadIdx.x;
  const int* row  = qw   + (int64_t)n * D_IN;
  uint16_t*  orow = wext + (int64_t)n * KEXT;
  const int base = t * 16;
#pragma unroll
  for (int j = 0; j < 4; j++) {
    i32x4 v = *(const i32x4*)(row + base + j * 4);
    u16x4 o;
#pragma unroll
    for (int e = 0; e < 4; e++) o[e] = f32_to_bf16((float)v[e]);  // exact
    *(u16x4*)(orow + base + j * 4) = o;
  }
  if (t < RANK) {
    float sr = (float)qscale[n] * meta[0];
    orow[D_IN + t] = f32_to_bf16(2.0f * loraB[n * RANK + t] / sr);
  } else if (t < 2 * RANK) {
    orow[D_IN + t] = (uint16_t)0;  // zero pad
  }
}

// ---- 4) main GEMM: 128x256 tile, BK=32, dbuf, 3 blocks/CU --------------
// 256 threads = 4 waves (1m x 4n), per-wave 128x64 (acc 8x4 frags, ~108
// VGPR as measured in R4). LDS = 2 dbuf x (A 8KB + B 16KB) = 48 KB ->
// 3 blocks/CU co-resident (12 waves): independent blocks fill each
// other's vmcnt/barrier stalls (m114), no spill (R6 post-mortem).
// 129 uniform K-tiles; fragment-native LDS (0 conflicts, 5 rounds).
extern "C" __global__ __launch_bounds__(256, 3) void k_gemm(
    const uint16_t* __restrict__ A, const uint16_t* __restrict__ B,
    const int* __restrict__ qscale, const float* __restrict__ meta,
    const float* __restrict__ bias, float* __restrict__ out) {
  extern __shared__ char ldsc[];               // 49152 B
  char* aB = ldsc;                             // [2][8192]
  char* bB = ldsc + 16384;                     // [2][16384]

  const int tid = threadIdx.x;
  const int bid = blockIdx.x;                  // 1024 blocks, %8==0
  const int xcd = bid & 7, loc = bid >> 3;     // bijective XCD swizzle
  const int mtile = xcd * 8 + (loc & 7);       // 0..63
  const int ntile = loc >> 3;                  // 0..15

  const int wn = tid >> 6, l = tid & 63;       // 4 waves = 4 n-slices
  const int l15 = l & 15, lk = l >> 4;
  const int fro = lk * 256 + l15 * 16;         // frag byte offset in 1024-B run

  const uint16_t* Ag = A + (int64_t)mtile * 128 * KEXT;
  const uint16_t* Bg = B + (int64_t)ntile * 256 * KEXT;

  // staging granule g = c*256 + tid: row = c*64 + row_lo, chunk from tid;
  // dest byte = g*16 (linear in lane within each wave).
  const int row_lo = ((tid >> 6) << 4) | (tid & 15);           // 0..63
  const int64_t s_base = (int64_t)row_lo * KEXT + ((tid >> 4) & 3) * 8;

#define STG_A(bufp, kb) {                                                     \
    gload16((bufp) + (size_t)tid * 16,          Ag + (kb) + s_base);          \
    gload16((bufp) + 4096 + (size_t)tid * 16,                                 \
            Ag + (kb) + (int64_t)64 * KEXT + s_base); }
#define STG_B(bufp, kb) {                                                     \
    gload16((bufp) + (size_t)tid * 16,          Bg + (kb) + s_base);          \
    gload16((bufp) + 4096 + (size_t)tid * 16,                                 \
            Bg + (kb) + (int64_t)64 * KEXT + s_base);                         \
    gload16((bufp) + 8192 + (size_t)tid * 16,                                 \
            Bg + (kb) + (int64_t)128 * KEXT + s_base);                        \
    gload16((bufp) + 12288 + (size_t)tid * 16,                                \
            Bg + (kb) + (int64_t)192 * KEXT + s_base); }

  f32x4a acc[8][4];
#pragma unroll
  for (int i = 0; i < 8; i++)
#pragma unroll
    for (int j = 0; j < 4; j++) acc[i][j] = (f32x4a){0.f, 0.f, 0.f, 0.f};

  // prologue: stage tile 0 into buf0 (6 loads)
  STG_A(aB, 0); STG_B(bB, 0);
  asm volatile("s_waitcnt vmcnt(0)" ::: "memory");
  asm volatile("s_barrier" ::: "memory");

  for (int kt = 0; kt < NTT; ++kt) {
    const int cur = kt & 1;
    const char* cA = aB + cur * 8192;
    const char* cB = bB + cur * 16384;
    char* nA = aB + (cur ^ 1) * 8192;
    char* nB = bB + (cur ^ 1) * 16384;
    const bool st = (kt + 1 < NTT);
    const int64_t kb = (int64_t)(kt + 1) * 32;

    // issue next-tile staging first: MFMA below covers its latency
    if (st) { STG_A(nA, kb); STG_B(nB, kb); }

    s16x8 bf[4], af[8];
#pragma unroll
    for (int ni = 0; ni < 4; ++ni)
      bf[ni] = *(const s16x8*)(cB + (wn * 4 + ni) * 1024 + fro);
#pragma unroll
    for (int mi = 0; mi < 8; ++mi)
      af[mi] = *(const s16x8*)(cA + mi * 1024 + fro);

    __builtin_amdgcn_s_setprio(1);
#pragma unroll
    for (int mi = 0; mi < 8; ++mi)
#pragma unroll
      for (int ni = 0; ni < 4; ++ni)
        acc[mi][ni] = __builtin_amdgcn_mfma_f32_16x16x32_bf16(
            af[mi], bf[ni], acc[mi][ni], 0, 0, 0);
    __builtin_amdgcn_s_setprio(0);

    if (st) {
      asm volatile("s_waitcnt vmcnt(0)" ::: "memory");
      asm volatile("s_barrier" ::: "memory");
    }
  }

  // epilogue: out = acc * (qscale[n]*meta) + bias[n]; nontemporal stores
  // so the 134-MB C stream doesn't evict A/B from L3.
  const float mv = meta[0];
  const int64_t mrow0 = (int64_t)mtile * 128;
  const int ncol0 = ntile * 256 + wn * 64;
#pragma unroll
  for (int ni = 0; ni < 4; ++ni) {
    int n = ncol0 + ni * 16 + l15;
    float sr = (float)qscale[n] * mv;
    float bv = bias[n];
#pragma unroll
    for (int mi = 0; mi < 8; ++mi) {
      float* op = out + (mrow0 + mi * 16 + lk * 4) * (int64_t)D_OUT + n;
#pragma unroll
      for (int reg = 0; reg < 4; reg++)
        __builtin_nontemporal_store(acc[mi][ni][reg] * sr + bv,
                                    op + (int64_t)reg * D_OUT);
    }
  }
#undef STG_A
#undef STG_B
}

extern "C" void kernel_launch(void* const* d_in, const int* in_sizes, int n_in,
                              void* d_out, int out_size, void* d_ws, size_t ws_size,
                              hipStream_t stream) {
  const float* x    = (const float*)d_in[0];
  const int*   qw   = (const int*)d_in[1];
  const int*   qs   = (const int*)d_in[2];
  const float* meta = (const float*)d_in[3];
  const float* bias = (const float*)d_in[4];
  const float* lA   = (const float*)d_in[5];
  const float* lB   = (const float*)d_in[6];
  float* out = (float*)d_out;

  uint16_t* xext = (uint16_t*)d_ws;                       // 8192*4128*2 B
  uint16_t* wext = xext + (size_t)MROWS * KEXT;           // 4096*4128*2 B
  const size_t need = ((size_t)MROWS + D_OUT) * KEXT * 2; // 101,449,728 B
  if (ws_size < need) return;

  const int lds_bytes = 49152;                            // 48 KB -> 3 blk/CU
  (void)hipFuncSetAttribute((const void*)k_gemm,
                            hipFuncAttributeMaxDynamicSharedMemorySize,
                            lds_bytes);

  k_conv_x<<<2048, 256, 0, stream>>>(x, xext);
  k_xa<<<MROWS / 64, 256, 0, stream>>>(xext, xext, lA);
  k_conv_w<<<D_OUT, 256, 0, stream>>>(qw, qs, meta, lB, wext);
  k_gemm<<<1024, 256, lds_bytes, stream>>>(xext, wext, qs, meta, bias, out);
}

// Round 8
// 392.516 us; speedup vs baseline: 9.1295x; 2.4394x over previous
//
#include <hip/hip_runtime.h>
#include <hip/hip_bf16.h>
#include <stdint.h>

typedef short   s16x8  __attribute__((ext_vector_type(8)));
typedef float   f32x4a __attribute__((ext_vector_type(4)));
typedef unsigned short u16x4 __attribute__((ext_vector_type(4)));
typedef int     i32x4  __attribute__((ext_vector_type(4)));

#define D_IN   4096
#define D_OUT  4096
#define RANK   16
#define KEXT   4128   // 4096 + 16 (lora) + 16 (zero pad) = 129 * 32
#define MROWS  8192   // 4 * 2048
#define NTT    129    // K-tiles of 32

__device__ __forceinline__ uint16_t f32_to_bf16(float f) {
  union { float f; uint32_t u; } v; v.f = f;
  uint32_t u = v.u;
  return (uint16_t)((u + 0x7FFFu + ((u >> 16) & 1u)) >> 16);  // RNE
}

__device__ __forceinline__ void gload16(void* lds, const void* g) {
  __builtin_amdgcn_global_load_lds(
      (const __attribute__((address_space(1))) uint32_t*)g,
      (__attribute__((address_space(3))) uint32_t*)lds, 16, 0, 0);
}

// ---- 1) x fp32 -> bf16 into x_ext (row stride KEXT) --------------------
extern "C" __global__ void k_conv_x(const float* __restrict__ x,
                                    uint16_t* __restrict__ xext) {
  int64_t idx = (int64_t)blockIdx.x * blockDim.x + threadIdx.x;  // float4 index
  const int64_t total  = (int64_t)MROWS * (D_IN / 4);
  const int64_t stride = (int64_t)gridDim.x * blockDim.x;
  for (; idx < total; idx += stride) {
    int64_t m = idx >> 10;              // D_IN/4 = 1024
    int k4 = (int)(idx & 1023);
    f32x4a v = *(const f32x4a*)(x + m * D_IN + (int64_t)k4 * 4);
    u16x4 o;
#pragma unroll
    for (int j = 0; j < 4; j++) o[j] = f32_to_bf16(v[j]);
    *(u16x4*)(xext + m * KEXT + k4 * 4) = o;
  }
}

// ---- 2) xA = x_bf16 @ loraA^T via MFMA, into x_ext cols [4096,4128) ----
extern "C" __global__ __launch_bounds__(256) void k_xa(
    const uint16_t* __restrict__ xext_ro, uint16_t* __restrict__ xext_rw,
    const float* __restrict__ loraA) {
  const int tid = threadIdx.x, w = tid >> 6, l = tid & 63;
  const int l15 = l & 15, lk = l >> 4;
  const int64_t row0 = (int64_t)blockIdx.x * 64 + w * 16;
  f32x4a acc = {0.f, 0.f, 0.f, 0.f};
  const uint16_t* xrow = xext_ro + (row0 + l15) * KEXT + lk * 8;
  const float*    arow = loraA + (int64_t)l15 * D_IN + lk * 8;
  for (int k0 = 0; k0 < D_IN; k0 += 32) {
    s16x8 af = *(const s16x8*)(xrow + k0);
    s16x8 bf;
#pragma unroll
    for (int j = 0; j < 8; j++) bf[j] = (short)f32_to_bf16(arow[k0 + j]);
    acc = __builtin_amdgcn_mfma_f32_16x16x32_bf16(af, bf, acc, 0, 0, 0);
  }
#pragma unroll
  for (int reg = 0; reg < 4; reg++) {
    int64_t m = row0 + lk * 4 + reg;
    xext_rw[m * KEXT + D_IN + l15]        = f32_to_bf16(acc[reg]);
    xext_rw[m * KEXT + D_IN + RANK + l15] = (uint16_t)0;  // zero pad
  }
}

// ---- 3) qweight int -> bf16 + LoRA-B tail into w_ext -------------------
extern "C" __global__ void k_conv_w(const int* __restrict__ qw,
                                    const int* __restrict__ qscale,
                                    const float* __restrict__ meta,
                                    const float* __restrict__ loraB,
                                    uint16_t* __restrict__ wext) {
  const int n = blockIdx.x, t = threadIdx.x;
  const int* row  = qw   + (int64_t)n * D_IN;
  uint16_t*  orow = wext + (int64_t)n * KEXT;
  const int base = t * 16;
#pragma unroll
  for (int j = 0; j < 4; j++) {
    i32x4 v = *(const i32x4*)(row + base + j * 4);
    u16x4 o;
#pragma unroll
    for (int e = 0; e < 4; e++) o[e] = f32_to_bf16((float)v[e]);  // exact
    *(u16x4*)(orow + base + j * 4) = o;
  }
  if (t < RANK) {
    float sr = (float)qscale[n] * meta[0];
    orow[D_IN + t] = f32_to_bf16(2.0f * loraB[n * RANK + t] / sr);
  } else if (t < 2 * RANK) {
    orow[D_IN + t] = (uint16_t)0;  // zero pad
  }
}

// ---- 4) main GEMM: 128x256 tile, BK=32, dbuf, 2 blocks/CU --------------
// 256 threads = 4 waves (1m x 4n), per-wave 128x64. Regs: 128 acc (AGPR,
// unified file) + ~90 VGPR ~= 218 -> __launch_bounds__(256,2) caps at 256:
// NO spill (R6/R7 post-mortem: any cap < 220 spills the accumulator and
// craters to GB-scale scratch traffic). LDS 48 KB -> 2 blocks/CU: two
// UNSYNCHRONIZED 4-wave blocks per CU fill each other's vmcnt/barrier
// stalls (m114 overlap) -- same 8 waves/CU as R4 but not barrier-locked.
extern "C" __global__ __launch_bounds__(256, 2) void k_gemm(
    const uint16_t* __restrict__ A, const uint16_t* __restrict__ B,
    const int* __restrict__ qscale, const float* __restrict__ meta,
    const float* __restrict__ bias, float* __restrict__ out) {
  extern __shared__ char ldsc[];               // 49152 B
  char* aB = ldsc;                             // [2][8192]
  char* bB = ldsc + 16384;                     // [2][16384]

  const int tid = threadIdx.x;
  const int bid = blockIdx.x;                  // 1024 blocks, %8==0
  const int xcd = bid & 7, loc = bid >> 3;     // bijective XCD swizzle
  const int mtile = xcd * 8 + (loc & 7);       // 0..63
  const int ntile = loc >> 3;                  // 0..15

  const int wn = tid >> 6, l = tid & 63;       // 4 waves = 4 n-slices
  const int l15 = l & 15, lk = l >> 4;
  const int fro = lk * 256 + l15 * 16;         // frag byte offset in 1024-B run

  const uint16_t* Ag = A + (int64_t)mtile * 128 * KEXT;
  const uint16_t* Bg = B + (int64_t)ntile * 256 * KEXT;

  const int row_lo = ((tid >> 6) << 4) | (tid & 15);           // 0..63
  const int64_t s_base = (int64_t)row_lo * KEXT + ((tid >> 4) & 3) * 8;

#define STG_A(bufp, kb) {                                                     \
    gload16((bufp) + (size_t)tid * 16,          Ag + (kb) + s_base);          \
    gload16((bufp) + 4096 + (size_t)tid * 16,                                 \
            Ag + (kb) + (int64_t)64 * KEXT + s_base); }
#define STG_B(bufp, kb) {                                                     \
    gload16((bufp) + (size_t)tid * 16,          Bg + (kb) + s_base);          \
    gload16((bufp) + 4096 + (size_t)tid * 16,                                 \
            Bg + (kb) + (int64_t)64 * KEXT + s_base);                         \
    gload16((bufp) + 8192 + (size_t)tid * 16,                                 \
            Bg + (kb) + (int64_t)128 * KEXT + s_base);                        \
    gload16((bufp) + 12288 + (size_t)tid * 16,                                \
            Bg + (kb) + (int64_t)192 * KEXT + s_base); }

  f32x4a acc[8][4];
#pragma unroll
  for (int i = 0; i < 8; i++)
#pragma unroll
    for (int j = 0; j < 4; j++) acc[i][j] = (f32x4a){0.f, 0.f, 0.f, 0.f};

  // prologue: stage tile 0 into buf0 (6 loads)
  STG_A(aB, 0); STG_B(bB, 0);
  asm volatile("s_waitcnt vmcnt(0)" ::: "memory");
  asm volatile("s_barrier" ::: "memory");

  for (int kt = 0; kt < NTT; ++kt) {
    const int cur = kt & 1;
    const char* cA = aB + cur * 8192;
    const char* cB = bB + cur * 16384;
    char* nA = aB + (cur ^ 1) * 8192;
    char* nB = bB + (cur ^ 1) * 16384;
    const bool st = (kt + 1 < NTT);
    const int64_t kb = (int64_t)(kt + 1) * 32;

    // issue next-tile staging first: MFMA below covers its latency
    if (st) { STG_A(nA, kb); STG_B(nB, kb); }

    s16x8 bf[4], af[8];
#pragma unroll
    for (int ni = 0; ni < 4; ++ni)
      bf[ni] = *(const s16x8*)(cB + (wn * 4 + ni) * 1024 + fro);
#pragma unroll
    for (int mi = 0; mi < 8; ++mi)
      af[mi] = *(const s16x8*)(cA + mi * 1024 + fro);

    __builtin_amdgcn_s_setprio(1);
#pragma unroll
    for (int mi = 0; mi < 8; ++mi)
#pragma unroll
      for (int ni = 0; ni < 4; ++ni)
        acc[mi][ni] = __builtin_amdgcn_mfma_f32_16x16x32_bf16(
            af[mi], bf[ni], acc[mi][ni], 0, 0, 0);
    __builtin_amdgcn_s_setprio(0);

    if (st) {
      asm volatile("s_waitcnt vmcnt(0)" ::: "memory");
      asm volatile("s_barrier" ::: "memory");
    }
  }

  // epilogue: out = acc * (qscale[n]*meta) + bias[n]; nontemporal stores
  // so the 134-MB C stream doesn't evict A/B from L3.
  const float mv = meta[0];
  const int64_t mrow0 = (int64_t)mtile * 128;
  const int ncol0 = ntile * 256 + wn * 64;
#pragma unroll
  for (int ni = 0; ni < 4; ++ni) {
    int n = ncol0 + ni * 16 + l15;
    float sr = (float)qscale[n] * mv;
    float bv = bias[n];
#pragma unroll
    for (int mi = 0; mi < 8; ++mi) {
      float* op = out + (mrow0 + mi * 16 + lk * 4) * (int64_t)D_OUT + n;
#pragma unroll
      for (int reg = 0; reg < 4; reg++)
        __builtin_nontemporal_store(acc[mi][ni][reg] * sr + bv,
                                    op + (int64_t)reg * D_OUT);
    }
  }
#undef STG_A
#undef STG_B
}

extern "C" void kernel_launch(void* const* d_in, const int* in_sizes, int n_in,
                              void* d_out, int out_size, void* d_ws, size_t ws_size,
                              hipStream_t stream) {
  const float* x    = (const float*)d_in[0];
  const int*   qw   = (const int*)d_in[1];
  const int*   qs   = (const int*)d_in[2];
  const float* meta = (const float*)d_in[3];
  const float* bias = (const float*)d_in[4];
  const float* lA   = (const float*)d_in[5];
  const float* lB   = (const float*)d_in[6];
  float* out = (float*)d_out;

  uint16_t* xext = (uint16_t*)d_ws;                       // 8192*4128*2 B
  uint16_t* wext = xext + (size_t)MROWS * KEXT;           // 4096*4128*2 B
  const size_t need = ((size_t)MROWS + D_OUT) * KEXT * 2; // 101,449,728 B
  if (ws_size < need) return;

  const int lds_bytes = 49152;                            // 48 KB -> 2 blk/CU
  (void)hipFuncSetAttribute((const void*)k_gemm,
                            hipFuncAttributeMaxDynamicSharedMemorySize,
                            lds_bytes);

  k_conv_x<<<2048, 256, 0, stream>>>(x, xext);
  k_xa<<<MROWS / 64, 256, 0, stream>>>(xext, xext, lA);
  k_conv_w<<<D_OUT, 256, 0, stream>>>(qw, qs, meta, lB, wext);
  k_gemm<<<1024, 256, lds_bytes, stream>>>(xext, wext, qs, meta, bias, out);
}

// Round 9
// 331.084 us; speedup vs baseline: 10.8235x; 1.1855x over previous
//
#include <hip/hip_runtime.h>
#include <hip/hip_bf16.h>
#include <stdint.h>

typedef short   s16x8  __attribute__((ext_vector_type(8)));
typedef float   f32x4a __attribute__((ext_vector_type(4)));
typedef unsigned short u16x4 __attribute__((ext_vector_type(4)));
typedef int     i32x4  __attribute__((ext_vector_type(4)));

#define D_IN   4096
#define D_OUT  4096
#define RANK   16
#define KEXT   4128   // 4096 + 16 (lora) + 16 (zero pad) = 129 * 32
#define MROWS  8192   // 4 * 2048
#define NTT    129    // K-tiles of 32

__device__ __forceinline__ uint16_t f32_to_bf16(float f) {
  union { float f; uint32_t u; } v; v.f = f;
  uint32_t u = v.u;
  return (uint16_t)((u + 0x7FFFu + ((u >> 16) & 1u)) >> 16);  // RNE
}

__device__ __forceinline__ void gload16(void* lds, const void* g) {
  __builtin_amdgcn_global_load_lds(
      (const __attribute__((address_space(1))) uint32_t*)g,
      (__attribute__((address_space(3))) uint32_t*)lds, 16, 0, 0);
}

// ---- 1) x fp32 -> bf16 into x_ext (row stride KEXT) --------------------
extern "C" __global__ void k_conv_x(const float* __restrict__ x,
                                    uint16_t* __restrict__ xext) {
  int64_t idx = (int64_t)blockIdx.x * blockDim.x + threadIdx.x;  // float4 index
  const int64_t total  = (int64_t)MROWS * (D_IN / 4);
  const int64_t stride = (int64_t)gridDim.x * blockDim.x;
  for (; idx < total; idx += stride) {
    int64_t m = idx >> 10;              // D_IN/4 = 1024
    int k4 = (int)(idx & 1023);
    f32x4a v = *(const f32x4a*)(x + m * D_IN + (int64_t)k4 * 4);
    u16x4 o;
#pragma unroll
    for (int j = 0; j < 4; j++) o[j] = f32_to_bf16(v[j]);
    *(u16x4*)(xext + m * KEXT + k4 * 4) = o;
  }
}

// ---- 2) xA = x_bf16 @ loraA^T via MFMA, into x_ext cols [4096,4128) ----
extern "C" __global__ __launch_bounds__(256) void k_xa(
    const uint16_t* __restrict__ xext_ro, uint16_t* __restrict__ xext_rw,
    const float* __restrict__ loraA) {
  const int tid = threadIdx.x, w = tid >> 6, l = tid & 63;
  const int l15 = l & 15, lk = l >> 4;
  const int64_t row0 = (int64_t)blockIdx.x * 64 + w * 16;
  f32x4a acc = {0.f, 0.f, 0.f, 0.f};
  const uint16_t* xrow = xext_ro + (row0 + l15) * KEXT + lk * 8;
  const float*    arow = loraA + (int64_t)l15 * D_IN + lk * 8;
  for (int k0 = 0; k0 < D_IN; k0 += 32) {
    s16x8 af = *(const s16x8*)(xrow + k0);
    s16x8 bf;
#pragma unroll
    for (int j = 0; j < 8; j++) bf[j] = (short)f32_to_bf16(arow[k0 + j]);
    acc = __builtin_amdgcn_mfma_f32_16x16x32_bf16(af, bf, acc, 0, 0, 0);
  }
#pragma unroll
  for (int reg = 0; reg < 4; reg++) {
    int64_t m = row0 + lk * 4 + reg;
    xext_rw[m * KEXT + D_IN + l15]        = f32_to_bf16(acc[reg]);
    xext_rw[m * KEXT + D_IN + RANK + l15] = (uint16_t)0;  // zero pad
  }
}

// ---- 3) qweight int -> bf16 + LoRA-B tail into w_ext -------------------
extern "C" __global__ void k_conv_w(const int* __restrict__ qw,
                                    const int* __restrict__ qscale,
                                    const float* __restrict__ meta,
                                    const float* __restrict__ loraB,
                                    uint16_t* __restrict__ wext) {
  const int n = blockIdx.x, t = threadIdx.x;
  const int* row  = qw   + (int64_t)n * D_IN;
  uint16_t*  orow = wext + (int64_t)n * KEXT;
  const int base = t * 16;
#pragma unroll
  for (int j = 0; j < 4; j++) {
    i32x4 v = *(const i32x4*)(row + base + j * 4);
    u16x4 o;
#pragma unroll
    for (int e = 0; e < 4; e++) o[e] = f32_to_bf16((float)v[e]);  // exact
    *(u16x4*)(orow + base + j * 4) = o;
  }
  if (t < RANK) {
    float sr = (float)qscale[n] * meta[0];
    orow[D_IN + t] = f32_to_bf16(2.0f * loraB[n * RANK + t] / sr);
  } else if (t < 2 * RANK) {
    orow[D_IN + t] = (uint16_t)0;  // zero pad
  }
}

// ---- 4) main GEMM: 256x256 tile, BK=32, 4-slot LDS rotation ------------
// 8 waves (2m x 4n), per-wave 128x64 (R4's proven geometry). LDS 128 KB:
// A,B x 4 slots x 16 KB. At tile kt we stage tile kt+3 into slot
// (kt+3)&3 = (kt-1)&3 (readers passed the end-of-(kt-1) barrier -> WAR
// safe). Steady-state 12 loads in flight; end-of-tile wait vmcnt(8)
// (2 tiles of slack, m201's depth). 129 uniform K-tiles. Per tile:
// 2 phases x 16 MFMA with barrier/lgkm0/setprio (R4 pattern).
extern "C" __global__ __launch_bounds__(512, 2) void k_gemm(
    const uint16_t* __restrict__ A, const uint16_t* __restrict__ B,
    const int* __restrict__ qscale, const float* __restrict__ meta,
    const float* __restrict__ bias, float* __restrict__ out) {
  extern __shared__ char ldsc[];               // 131072 B
  char* aS = ldsc;                             // [4][16384]
  char* bS = ldsc + 65536;                     // [4][16384]

  const int tid = threadIdx.x;
  const int bid = blockIdx.x;                  // 512 blocks
  const int xcd = bid & 7, loc = bid >> 3;     // loc 0..63
  const int rnd = loc >> 5, r5 = loc & 31;     // 2 dispatch rounds
  const int mtile = xcd * 4 + rnd * 2 + (r5 >> 4);  // 0..31 (bijective)
  const int ntile = r5 & 15;                   // 0..15; round 2 reuses all
                                               // 16 B-panels (L3-hot)
  const int w = tid >> 6, l = tid & 63;
  const int wm = w >> 2, wn = w & 3;
  const int l15 = l & 15, lk = l >> 4;
  const int fro = lk * 256 + l15 * 16;         // frag byte offset in 1024-B run

  const uint16_t* Ag = A + (int64_t)mtile * 256 * KEXT;
  const uint16_t* Bg = B + (int64_t)ntile * 256 * KEXT;

  // staging granule: row = (tid>>6)*16 + (tid&15), kchunk = (tid>>4)&3;
  // two calls cover rows 0..127 / 128..255; dest linear (g*16).
  const int row_lo = ((tid >> 6) << 4) | (tid & 15);
  const int64_t s_lo = (int64_t)row_lo * KEXT + ((tid >> 4) & 3) * 8;
  const int64_t s_hi = s_lo + (int64_t)128 * KEXT;

#define STG_A(sl, kb) { char* p_ = aS + (sl) * 16384;                  \
    gload16(p_ + (size_t)tid * 16,        Ag + (kb) + s_lo);           \
    gload16(p_ + 8192 + (size_t)tid * 16, Ag + (kb) + s_hi); }
#define STG_B(sl, kb) { char* p_ = bS + (sl) * 16384;                  \
    gload16(p_ + (size_t)tid * 16,        Bg + (kb) + s_lo);           \
    gload16(p_ + 8192 + (size_t)tid * 16, Bg + (kb) + s_hi); }

  f32x4a acc[8][4];
#pragma unroll
  for (int i = 0; i < 8; i++)
#pragma unroll
    for (int j = 0; j < 4; j++) acc[i][j] = (f32x4a){0.f, 0.f, 0.f, 0.f};

  // prologue: stage tiles 0,1,2 into slots 0,1,2 (12 loads/wave);
  // wait until tile 0 done (8 = tiles 1,2 still in flight).
  STG_A(0, 0); STG_B(0, 0);
  STG_A(1, 32); STG_B(1, 32);
  STG_A(2, 64); STG_B(2, 64);
  asm volatile("s_waitcnt vmcnt(8)" ::: "memory");
  asm volatile("s_barrier" ::: "memory");

  for (int kt = 0; kt < NTT; ++kt) {
    const int sl = kt & 3;
    const char* cA = aS + sl * 16384;
    const char* cB = bS + sl * 16384;
    const bool st = (kt + 3 < NTT);
    const int s3 = (kt + 3) & 3;
    const int64_t kb3 = (int64_t)(kt + 3) * 32;

    // ---- phase 0: mi 0..3 ----
    if (st) STG_A(s3, kb3);
    s16x8 bf[4], af[4];
#pragma unroll
    for (int ni = 0; ni < 4; ++ni)
      bf[ni] = *(const s16x8*)(cB + (wn * 4 + ni) * 1024 + fro);
#pragma unroll
    for (int mi = 0; mi < 4; ++mi)
      af[mi] = *(const s16x8*)(cA + (wm * 8 + mi) * 1024 + fro);
    asm volatile("s_barrier" ::: "memory");
    asm volatile("s_waitcnt lgkmcnt(0)" ::: "memory");
    __builtin_amdgcn_s_setprio(1);
#pragma unroll
    for (int mi = 0; mi < 4; ++mi)
#pragma unroll
      for (int ni = 0; ni < 4; ++ni)
        acc[mi][ni] = __builtin_amdgcn_mfma_f32_16x16x32_bf16(
            af[mi], bf[ni], acc[mi][ni], 0, 0, 0);
    __builtin_amdgcn_s_setprio(0);
    asm volatile("s_barrier" ::: "memory");

    // ---- phase 1: mi 4..7 ----
    if (st) STG_B(s3, kb3);
#pragma unroll
    for (int mi = 0; mi < 4; ++mi)
      af[mi] = *(const s16x8*)(cA + (wm * 8 + 4 + mi) * 1024 + fro);
    asm volatile("s_barrier" ::: "memory");
    asm volatile("s_waitcnt lgkmcnt(0)" ::: "memory");
    __builtin_amdgcn_s_setprio(1);
#pragma unroll
    for (int mi = 0; mi < 4; ++mi)
#pragma unroll
      for (int ni = 0; ni < 4; ++ni)
        acc[4 + mi][ni] = __builtin_amdgcn_mfma_f32_16x16x32_bf16(
            af[mi], bf[ni], acc[4 + mi][ni], 0, 0, 0);
    __builtin_amdgcn_s_setprio(0);
    // end-of-tile wait: ensure tile kt+1 landed; keep kt+2/kt+3 in flight.
    if (kt + 3 < NTT)       asm volatile("s_waitcnt vmcnt(8)" ::: "memory");
    else if (kt + 2 < NTT)  asm volatile("s_waitcnt vmcnt(4)" ::: "memory");
    else if (kt + 1 < NTT)  asm volatile("s_waitcnt vmcnt(0)" ::: "memory");
    asm volatile("s_barrier" ::: "memory");
  }

  // epilogue: out = acc * (qscale[n]*meta) + bias[n]; nontemporal stores
  // keep the 134-MB C stream from evicting B panels in L3.
  const float mv = meta[0];
  const int64_t mrow0 = (int64_t)mtile * 256 + wm * 128;
  const int ncol0 = ntile * 256 + wn * 64;
#pragma unroll
  for (int ni = 0; ni < 4; ++ni) {
    int n = ncol0 + ni * 16 + l15;
    float sr = (float)qscale[n] * mv;
    float bv = bias[n];
#pragma unroll
    for (int mi = 0; mi < 8; ++mi) {
      float* op = out + (mrow0 + mi * 16 + lk * 4) * (int64_t)D_OUT + n;
#pragma unroll
      for (int reg = 0; reg < 4; reg++)
        __builtin_nontemporal_store(acc[mi][ni][reg] * sr + bv,
                                    op + (int64_t)reg * D_OUT);
    }
  }
#undef STG_A
#undef STG_B
}

extern "C" void kernel_launch(void* const* d_in, const int* in_sizes, int n_in,
                              void* d_out, int out_size, void* d_ws, size_t ws_size,
                              hipStream_t stream) {
  const float* x    = (const float*)d_in[0];
  const int*   qw   = (const int*)d_in[1];
  const int*   qs   = (const int*)d_in[2];
  const float* meta = (const float*)d_in[3];
  const float* bias = (const float*)d_in[4];
  const float* lA   = (const float*)d_in[5];
  const float* lB   = (const float*)d_in[6];
  float* out = (float*)d_out;

  uint16_t* xext = (uint16_t*)d_ws;                       // 8192*4128*2 B
  uint16_t* wext = xext + (size_t)MROWS * KEXT;           // 4096*4128*2 B
  const size_t need = ((size_t)MROWS + D_OUT) * KEXT * 2; // 101,449,728 B
  if (ws_size < need) return;

  const int lds_bytes = 131072;                           // 128 KB
  (void)hipFuncSetAttribute((const void*)k_gemm,
                            hipFuncAttributeMaxDynamicSharedMemorySize,
                            lds_bytes);

  k_conv_x<<<2048, 256, 0, stream>>>(x, xext);
  k_xa<<<MROWS / 64, 256, 0, stream>>>(xext, xext, lA);
  k_conv_w<<<D_OUT, 256, 0, stream>>>(qw, qs, meta, lB, wext);
  k_gemm<<<512, 512, lds_bytes, stream>>>(xext, wext, qs, meta, bias, out);
}